// Round 14
// baseline (277.488 us; speedup 1.0000x reference)
//
#include <hip/hip_runtime.h>

// 3-layer GraphSAGE, N=100000, F=H=128, E=1.6M.
// bf16 features, weights hi/lo split -> 2-term MFMA.
// R13 structure (single row-major activations + per-wave LDS-staged GEMM
// tiles, swizzled; fragment-order weights; swapped-operand MFMA; coalesced
// epilogue). THIS VERSION re-tiles k_sage2: 32 rows/wave (acc[2][8], ~130
// VGPR live) + launch_bounds(256,3) + 8KB/wave LDS -> 3 blocks/CU = 12
// waves/CU (was 2 blocks/CU, 8 waves) and a 782-block grid (finer tail).
// R7's version of this re-tile failed because loads were scattered; all
// sage2 accesses are now coalesced, so added TLP is pure gain. Bias/w3
// fragment loads moved to the epilogue to keep the main-loop live set low
// (R3 spill-trap awareness: ~40-reg slack vs the 170 budget).
// aggZ = R0 verified body (gather structural: ~59us / 3.3TB/s fill wall,
// FETCH at per-XCD dedupe floor -- R6/R10 splits refuted the alternative).

#define NN 100000
#define NB 391          // ceil(100000/256) buckets of 256 dst nodes
#define SLAB 5120       // slab capacity per bucket (mean 4096, sigma 64)

typedef short bf16x8 __attribute__((ext_vector_type(8)));
typedef float f32x4 __attribute__((ext_vector_type(4)));

static __device__ __forceinline__ float uaf(unsigned u) { return __uint_as_float(u); }
static __device__ __forceinline__ unsigned short f2bf(float f) {
  unsigned u = __float_as_uint(f);
  u += 0x7fffu + ((u >> 16) & 1u);
  return (unsigned short)(u >> 16);
}

// ---------------- fused prep: scatter | cvt_x | cvt_w | zero rows ----------------
__global__ __launch_bounds__(256) void k_prep(
    const int* __restrict__ src, const int* __restrict__ dst, int E, int SB,
    int* __restrict__ cursor, unsigned* __restrict__ pairs,
    const float* __restrict__ x, unsigned short* __restrict__ Zrm,
    const float* __restrict__ W1l, const float* __restrict__ W1r,
    const float* __restrict__ W2l, const float* __restrict__ W2r,
    unsigned short* __restrict__ wt1h, unsigned short* __restrict__ wt1l,
    unsigned short* __restrict__ wt2h, unsigned short* __restrict__ wt2l) {
  __shared__ int h[NB];
  __shared__ int rb[NB];
  const int b = blockIdx.x;
  const int tid = threadIdx.x;
  const int XB = NN * 16 / 256;  // 6250 cvt_x blocks

  if (b < SB) {
    // ---- edge scatter into bucket slabs ----
    for (int i = tid; i < NB; i += 256) h[i] = 0;
    __syncthreads();
    int s[8], d[8];
    const int base = b * 2048 + tid * 8;
    #pragma unroll
    for (int i = 0; i < 8; i++) {
      int g = base + i;
      bool ok = g < E;
      s[i] = ok ? src[g] : 0;
      d[i] = ok ? dst[g] : -1;
      if (ok) atomicAdd(&h[d[i] >> 8], 1);
    }
    __syncthreads();
    for (int i = tid; i < NB; i += 256) {
      rb[i] = h[i] ? atomicAdd(&cursor[i], h[i]) : 0;
      h[i] = 0;
    }
    __syncthreads();
    #pragma unroll
    for (int i = 0; i < 8; i++) {
      if (d[i] >= 0) {
        int bk = d[i] >> 8;
        int off = rb[bk] + atomicAdd(&h[bk], 1);
        if (off < SLAB)
          pairs[(size_t)bk * SLAB + off] =
              ((unsigned)(d[i] & 255) << 17) | (unsigned)s[i];
      }
    }
  } else if (b < SB + XB) {
    // ---- x fp32 -> bf16 row-major root rows ----
    int t = (b - SB) * 256 + tid;      // t < N*16
    int node = t >> 4, c = t & 15;
    const float4* xp = (const float4*)(x + (size_t)node * 128 + c * 8);
    float4 a = xp[0], bb = xp[1];
    float v[8] = {a.x, a.y, a.z, a.w, bb.x, bb.y, bb.z, bb.w};
    unsigned hh[8];
    #pragma unroll
    for (int i = 0; i < 8; i++) hh[i] = f2bf(v[i]);
    uint4 p;
    p.x = hh[0] | (hh[1] << 16); p.y = hh[2] | (hh[3] << 16);
    p.z = hh[4] | (hh[5] << 16); p.w = hh[6] | (hh[7] << 16);
    *(uint4*)(Zrm + (size_t)node * 128 + c * 8) = p;
  } else if (b < SB + XB + 64) {
    // ---- weight transpose + hi/lo split, MFMA-fragment layout ----
    //   frag = (nn>>4)*8 + (k>>7)*4 + ((k>>5)&3); lane = ((k>>3)&3)*16+(nn&15)
    #pragma unroll
    for (int it = 0; it < 4; it++) {
      int t = (b - SB - XB) * 1024 + it * 256 + tid;  // t < 65536
      int layer = t >> 15;
      int rem = t & 32767;
      int k = rem >> 7;
      int nn = rem & 127;
      const float* Wl = layer ? W2l : W1l;
      const float* Wr = layer ? W2r : W1r;
      float v = (k < 128) ? Wl[k * 128 + nn] : Wr[(k - 128) * 128 + nn];
      unsigned short hv = f2bf(v);
      unsigned short lv = f2bf(v - uaf(((unsigned)hv) << 16));
      const int frag = (nn >> 4) * 8 + (k >> 7) * 4 + ((k >> 5) & 3);
      const int lane = ((k >> 3) & 3) * 16 + (nn & 15);
      const int addr = frag * 512 + lane * 8 + (k & 7);
      (layer ? wt2h : wt1h)[addr] = hv;
      (layer ? wt2l : wt1l)[addr] = lv;
    }
  } else {
    // ---- zero row N of Zrm (padding row for gather; stays 0 both layers) ----
    unsigned* zr = (unsigned*)(Zrm + (size_t)NN * 128);
    if (tid < 64) zr[tid] = 0;
  }
}

// ---------------- per-bucket CSR build ----------------
__global__ __launch_bounds__(256) void k_build(const unsigned* __restrict__ pairs,
                                               const int* __restrict__ cursor,
                                               int* __restrict__ beg, int* __restrict__ deg,
                                               int* __restrict__ csr, int N) {
  __shared__ int cnt[256];
  __shared__ int sd[256];
  __shared__ int cur[256];
  const int b = blockIdx.x;
  const int tid = threadIdx.x;
  const size_t p0 = (size_t)b * SLAB;
  int count = cursor[b];
  if (count > SLAB) count = SLAB;
  cnt[tid] = 0;
  cur[tid] = 0;
  __syncthreads();
  for (int i = tid; i < count; i += 256) atomicAdd(&cnt[pairs[p0 + i] >> 17], 1);
  __syncthreads();
  int v = cnt[tid];
  sd[tid] = v;
  __syncthreads();
  #pragma unroll
  for (int off = 1; off < 256; off <<= 1) {
    int u = (tid >= off) ? sd[tid - off] : 0;
    __syncthreads();
    sd[tid] += u;
    __syncthreads();
  }
  const int node = b * 256 + tid;
  if (node < N) {
    beg[node] = (int)p0 + (sd[tid] - v);
    deg[node] = v;
  }
  __syncthreads();
  for (int i = tid; i < count; i += 256) {
    unsigned pv = pairs[p0 + i];
    int dl = pv >> 17;
    int pos = (sd[dl] - cnt[dl]) + atomicAdd(&cur[dl], 1);
    csr[p0 + pos] = pv & 0x1ffff;
  }
}

// accumulate 8 bf16 (packed in uint4) into float acc[8] -- bit-exact unpack order
#define ACC8(v)                                   \
  acc[0] += uaf((v).x << 16);                     \
  acc[1] += uaf((v).x & 0xffff0000u);             \
  acc[2] += uaf((v).y << 16);                     \
  acc[3] += uaf((v).y & 0xffff0000u);             \
  acc[4] += uaf((v).z << 16);                     \
  acc[5] += uaf((v).z & 0xffff0000u);             \
  acc[6] += uaf((v).w << 16);                     \
  acc[7] += uaf((v).w & 0xffff0000u);

// ---------------- mean aggregation (R0 verified body; rm in, rm out) ----------------
__global__ __launch_bounds__(256) void k_aggZ(const unsigned short* __restrict__ Zrm,
                                              unsigned short* __restrict__ Zagg,
                                              const int* __restrict__ begA,
                                              const int* __restrict__ degA,
                                              const int* __restrict__ csr, int n) {
  const int wid = (blockIdx.x * blockDim.x + threadIdx.x) >> 6;
  const int lane = threadIdx.x & 63;
  if (wid >= n) return;
  const int beg = begA[wid];
  const int d = degA[wid];
  const int g = lane >> 4, c = lane & 15;
  float acc[8] = {0.f, 0.f, 0.f, 0.f, 0.f, 0.f, 0.f, 0.f};

  for (int base = 0; base < d; base += 64) {
    int m = d - base;
    if (m > 64) m = 64;
    int idx = csr[beg + base + (lane < m ? lane : 0)];
    for (int k = 0; k < m; k += 32) {
      uint4 vA[4], vB[4];
      const bool hasB = (k + 16) < m;
      #pragma unroll
      for (int u = 0; u < 4; u++) {
        int kk = k + u * 4 + g;
        int j = __shfl(idx, kk & 63);
        j = (kk < m) ? j : NN;  // zero row
        vA[u] = *(const uint4*)(Zrm + (size_t)j * 128 + c * 8);
      }
      if (hasB) {
        #pragma unroll
        for (int u = 0; u < 4; u++) {
          int kk = k + 16 + u * 4 + g;
          int j = __shfl(idx, kk & 63);
          j = (kk < m) ? j : NN;
          vB[u] = *(const uint4*)(Zrm + (size_t)j * 128 + c * 8);
        }
      }
      #pragma unroll
      for (int u = 0; u < 4; u++) { ACC8(vA[u]); }
      if (hasB) {
        #pragma unroll
        for (int u = 0; u < 4; u++) { ACC8(vB[u]); }
      }
    }
  }
  #pragma unroll
  for (int j = 0; j < 8; j++) {
    acc[j] += __shfl_xor(acc[j], 16);
    acc[j] += __shfl_xor(acc[j], 32);
  }
  const float inv = d > 0 ? 1.0f / (float)d : 0.f;
  if (g == 0) {
    unsigned h[8];
    #pragma unroll
    for (int j = 0; j < 8; j++) h[j] = f2bf(acc[j] * inv);
    uint4 p;
    p.x = h[0] | (h[1] << 16); p.y = h[2] | (h[3] << 16);
    p.z = h[4] | (h[5] << 16); p.w = h[6] | (h[7] << 16);
    *(uint4*)(Zagg + (size_t)wid * 128 + c * 8) = p;
  }
}

// ---------------- MFMA SAGE layer: 32 rows/wave, 3 blocks/CU ----------------
// Per wave: 32 contiguous rows. Per kh half: stage 8KB (8 coalesced 1KB
// loads) into private swizzled LDS tile, read 8 ds_read_b128 fragments.
// acc[s][cc] = mfma(W_frag, Z_frag, acc) (swapped operands): lane holds
// feat f'=cc*16+r16*4+r of node m0+s*16+ln. Bit-identical values to R13.
// MODE 0: relu -> Zout rows. MODE 1: fused layer-3 transform -> s2/r2.
template <int MODE>
__global__ __launch_bounds__(256, 3) void k_sage2(
    const unsigned short* __restrict__ Zagg, const unsigned short* __restrict__ Zroot,
    const unsigned short* __restrict__ WTh, const unsigned short* __restrict__ WTl,
    const float* __restrict__ bias, unsigned short* __restrict__ Zout,
    const float* __restrict__ w3l, const float* __restrict__ w3r,
    float* __restrict__ s2, float* __restrict__ r2, int n) {
  __shared__ __align__(16) unsigned short tile[4][4096];  // 8 KB per wave
  const int tid = threadIdx.x;
  const int lane = tid & 63;
  const int w = tid >> 6;
  const int ln = lane & 15;
  const int r16 = lane >> 4;
  const int m0 = blockIdx.x * 128 + w * 32;
  char* T = (char*)tile[w];

  f32x4 acc[2][8];
  #pragma unroll
  for (int s = 0; s < 2; s++)
    #pragma unroll
    for (int cc = 0; cc < 8; cc++) {
      acc[s][cc][0] = 0.f; acc[s][cc][1] = 0.f;
      acc[s][cc][2] = 0.f; acc[s][cc][3] = 0.f;
    }

  #pragma unroll
  for (int kh = 0; kh < 2; kh++) {
    const unsigned short* zsrc = kh ? Zroot : Zagg;
    // ---- stage 32 rows x 128 feats, XOR-swizzled (coalesced 1KB/instr) ----
    #pragma unroll
    for (int i = 0; i < 8; i++) {
      const int nl = i * 4 + r16;
      uint4 v = *(const uint4*)(zsrc + (size_t)(m0 + nl) * 128 + ln * 8);
      *(uint4*)(T + nl * 256 + ((ln * 16) ^ ((nl & 7) << 4))) = v;
    }
    // ---- fragment reads: a[s][ks][e] = Z[m0+s*16+ln][ks*32+r16*8+e] ----
    bf16x8 a[2][4];
    #pragma unroll
    for (int ks = 0; ks < 4; ks++)
      #pragma unroll
      for (int s = 0; s < 2; s++) {
        const int nl = s * 16 + ln;
        a[s][ks] = *(const bf16x8*)(T + nl * 256 +
                                    ((ks * 64 + r16 * 16) ^ ((nl & 7) << 4)));
      }
    // ---- MFMAs (same per-acc order as R13 -> bit-identical) ----
    #pragma unroll
    for (int ks = 0; ks < 4; ks++) {
      #pragma unroll
      for (int cg = 0; cg < 4; cg++) {
        bf16x8 bh[2], bl[2];
        #pragma unroll
        for (int j = 0; j < 2; j++) {
          const size_t o = (size_t)(((cg * 2 + j) * 8 + kh * 4 + ks) * 512 + lane * 8);
          bh[j] = *(const bf16x8*)(WTh + o);
          bl[j] = *(const bf16x8*)(WTl + o);
        }
        #pragma unroll
        for (int j = 0; j < 2; j++) {
          #pragma unroll
          for (int s = 0; s < 2; s++) {
            acc[s][cg * 2 + j] =
                __builtin_amdgcn_mfma_f32_16x16x32_bf16(bh[j], a[s][ks], acc[s][cg * 2 + j], 0, 0, 0);
            acc[s][cg * 2 + j] =
                __builtin_amdgcn_mfma_f32_16x16x32_bf16(bl[j], a[s][ks], acc[s][cg * 2 + j], 0, 0, 0);
          }
        }
      }
    }
  }

  if (MODE == 0) {
    float4 bv4[8];
    #pragma unroll
    for (int cc = 0; cc < 8; cc++) bv4[cc] = *(const float4*)(bias + cc * 16 + r16 * 4);
    #pragma unroll
    for (int s = 0; s < 2; s++) {
      const int node = m0 + s * 16 + ln;
      if (node < n) {
        unsigned short* op = Zout + (size_t)node * 128 + r16 * 4;
        #pragma unroll
        for (int cc = 0; cc < 8; cc++) {
          ushort4 hq;
          hq.x = f2bf(fmaxf(acc[s][cc][0] + bv4[cc].x, 0.f));
          hq.y = f2bf(fmaxf(acc[s][cc][1] + bv4[cc].y, 0.f));
          hq.z = f2bf(fmaxf(acc[s][cc][2] + bv4[cc].z, 0.f));
          hq.w = f2bf(fmaxf(acc[s][cc][3] + bv4[cc].w, 0.f));
          *(ushort4*)(op + cc * 16) = hq;
        }
      }
    }
  } else {
    float4 bv4[8], wl4[8], wr4[8];
    #pragma unroll
    for (int cc = 0; cc < 8; cc++) {
      bv4[cc] = *(const float4*)(bias + cc * 16 + r16 * 4);
      wl4[cc] = *(const float4*)(w3l + cc * 16 + r16 * 4);
      wr4[cc] = *(const float4*)(w3r + cc * 16 + r16 * 4);
    }
    #pragma unroll
    for (int s = 0; s < 2; s++) {
      float sl = 0.f, sr = 0.f;
      #pragma unroll
      for (int cc = 0; cc < 8; cc++) {
        float v0 = fmaxf(acc[s][cc][0] + bv4[cc].x, 0.f);
        float v1 = fmaxf(acc[s][cc][1] + bv4[cc].y, 0.f);
        float v2 = fmaxf(acc[s][cc][2] + bv4[cc].z, 0.f);
        float v3 = fmaxf(acc[s][cc][3] + bv4[cc].w, 0.f);
        sl += v0 * wl4[cc].x + v1 * wl4[cc].y + v2 * wl4[cc].z + v3 * wl4[cc].w;
        sr += v0 * wr4[cc].x + v1 * wr4[cc].y + v2 * wr4[cc].z + v3 * wr4[cc].w;
      }
      sl += __shfl_xor(sl, 16); sl += __shfl_xor(sl, 32);
      sr += __shfl_xor(sr, 16); sr += __shfl_xor(sr, 32);
      const int node = m0 + s * 16 + ln;
      if (r16 == 0 && node < n) {
        s2[node] = sl;
        r2[node] = sr;
      }
    }
  }
}

// ---------------- final scalar aggregation (16 lanes/node) ----------------
__global__ __launch_bounds__(256) void k_out3(const float* __restrict__ s2,
                                              const float* __restrict__ r2,
                                              const int* __restrict__ beg,
                                              const int* __restrict__ deg,
                                              const int* __restrict__ csr,
                                              const float* __restrict__ b3,
                                              float* __restrict__ out, int n) {
  int t = blockIdx.x * blockDim.x + threadIdx.x;
  int node = t >> 4;
  int ln = t & 15;
  if (node >= n) return;
  int bg = beg[node], d = deg[node];
  float s = 0.f;
  for (int i = ln; i < d; i += 16) s += s2[csr[bg + i]];
  s += __shfl_xor(s, 1); s += __shfl_xor(s, 2);
  s += __shfl_xor(s, 4); s += __shfl_xor(s, 8);
  if (ln == 0) out[node] = s / (d > 0 ? (float)d : 1.0f) + r2[node] + b3[0];
}

extern "C" void kernel_launch(void* const* d_in, const int* in_sizes, int n_in,
                              void* d_out, int out_size, void* d_ws, size_t ws_size,
                              hipStream_t stream) {
  const float* x   = (const float*)d_in[0];
  const int*   ei  = (const int*)d_in[1];
  const float* W1l = (const float*)d_in[2];
  const float* W1r = (const float*)d_in[3];
  const float* b1  = (const float*)d_in[4];
  const float* W2l = (const float*)d_in[5];
  const float* W2r = (const float*)d_in[6];
  const float* b2  = (const float*)d_in[7];
  const float* W3l = (const float*)d_in[8];
  const float* W3r = (const float*)d_in[9];
  const float* b3  = (const float*)d_in[10];
  float* out = (float*)d_out;

  const int N = NN;
  const int E = in_sizes[1] / 2;
  const int* src = ei;
  const int* dst = ei + E;

  char* ws = (char*)d_ws;
  size_t off = 0;
  auto alloc = [&](size_t bytes) -> char* {
    char* p = ws + off;
    off = (off + bytes + 255) & ~(size_t)255;
    return p;
  };
  int* cursor = (int*)alloc((NB + 1) * 4);
  unsigned* pairs = (unsigned*)alloc((size_t)NB * SLAB * 4);
  int* csr  = (int*)alloc(((size_t)NB * SLAB + 128) * 4);
  int* beg  = (int*)alloc((size_t)N * 4);
  int* deg  = (int*)alloc((size_t)N * 4);
  float* s2 = (float*)alloc((size_t)N * 4);
  float* r2 = (float*)alloc((size_t)N * 4);
  unsigned short* wt1h = (unsigned short*)alloc(128 * 256 * 2);
  unsigned short* wt1l = (unsigned short*)alloc(128 * 256 * 2);
  unsigned short* wt2h = (unsigned short*)alloc(128 * 256 * 2);
  unsigned short* wt2l = (unsigned short*)alloc(128 * 256 * 2);
  // +160 slack rows: sage2 tail-block staging reads up to row 100,095;
  // row NN is the zero pad for the gather (prep zeroes it, epilogue guards it).
  unsigned short* Zrm  = (unsigned short*)alloc((size_t)(N + 160) * 128 * 2);
  unsigned short* Zagg = (unsigned short*)alloc((size_t)(N + 160) * 128 * 2);

  hipMemsetAsync(cursor, 0, (NB + 1) * 4, stream);

  // ---- fused prep: edge scatter | x->bf16 | weight split | zero row ----
  const int SB = (E + 2047) / 2048;         // 782 scatter blocks
  const int XB = N * 16 / 256;              // 6250 cvt_x blocks
  k_prep<<<SB + XB + 64 + 1, 256, 0, stream>>>(
      src, dst, E, SB, cursor, pairs, x, Zrm,
      W1l, W1r, W2l, W2r, wt1h, wt1l, wt2h, wt2l);
  k_build<<<NB, 256, 0, stream>>>(pairs, cursor, beg, deg, csr, N);

  const int wb = (N * 64 + 255) / 256;
  const int sb = (N + 127) / 128;           // 782 GEMM blocks (32 rows/wave)
  // ---- layer 1 ----
  k_aggZ<<<wb, 256, 0, stream>>>(Zrm, Zagg, beg, deg, csr, N);
  k_sage2<0><<<sb, 256, 0, stream>>>(Zagg, Zrm, wt1h, wt1l, b1, Zrm,
                                     nullptr, nullptr, nullptr, nullptr, N);
  // ---- layer 2 (+ fused layer-3 transform) ----
  k_aggZ<<<wb, 256, 0, stream>>>(Zrm, Zagg, beg, deg, csr, N);
  k_sage2<1><<<sb, 256, 0, stream>>>(Zagg, Zrm, wt2h, wt2l, b2, nullptr,
                                     W3l, W3r, s2, r2, N);
  // ---- layer 3 scalar aggregation ----
  k_out3<<<(N * 16 + 255) / 256, 256, 0, stream>>>(s2, r2, beg, deg, csr, b3, out, N);
}

// Round 15
// 241.525 us; speedup vs baseline: 1.1489x; 1.1489x over previous
//
#include <hip/hip_runtime.h>

// 3-layer GraphSAGE, N=100000, F=H=128, E=1.6M.
// bf16 features, SINGLE-TERM bf16 weights (hi/lo split dropped).
// R13 structure: single row-major activations + per-wave LDS-staged GEMM
// tiles (XOR-swizzled), fragment-order weights, swapped-operand MFMA,
// coalesced epilogue, 64 rows/wave, 391 GEMM blocks.
// THIS VERSION drops the weight lo-term: R7/R14 proved sage2's cost scales
// with weight-load instrs (tile shrink doubled per-row weight traffic and
// lost both times), so the 2-term split -- 2x weight loads + 2x MFMA -- is
// the remaining big cost. Error budget: activations are already 1xbf16
// (rel ~2^-9) at every stage; dropping weight-lo adds a comparable
// independent term -> absmax ~0.011-0.016 vs threshold 0.0389 (5x headroom
// at R13's 0.0078). aggZ = R0 verified body (gather structural: ~59us /
// 3.3TB/s fill wall, FETCH at per-XCD dedupe floor -- R6/R10 refuted).

#define NN 100000
#define NB 391          // ceil(100000/256) buckets of 256 dst nodes
#define SLAB 5120       // slab capacity per bucket (mean 4096, sigma 64)

typedef short bf16x8 __attribute__((ext_vector_type(8)));
typedef float f32x4 __attribute__((ext_vector_type(4)));

static __device__ __forceinline__ float uaf(unsigned u) { return __uint_as_float(u); }
static __device__ __forceinline__ unsigned short f2bf(float f) {
  unsigned u = __float_as_uint(f);
  u += 0x7fffu + ((u >> 16) & 1u);
  return (unsigned short)(u >> 16);
}

// ---------------- fused prep: scatter | cvt_x | cvt_w | zero rows ----------------
__global__ __launch_bounds__(256) void k_prep(
    const int* __restrict__ src, const int* __restrict__ dst, int E, int SB,
    int* __restrict__ cursor, unsigned* __restrict__ pairs,
    const float* __restrict__ x, unsigned short* __restrict__ Zrm,
    const float* __restrict__ W1l, const float* __restrict__ W1r,
    const float* __restrict__ W2l, const float* __restrict__ W2r,
    unsigned short* __restrict__ wt1, unsigned short* __restrict__ wt2) {
  __shared__ int h[NB];
  __shared__ int rb[NB];
  const int b = blockIdx.x;
  const int tid = threadIdx.x;
  const int XB = NN * 16 / 256;  // 6250 cvt_x blocks

  if (b < SB) {
    // ---- edge scatter into bucket slabs ----
    for (int i = tid; i < NB; i += 256) h[i] = 0;
    __syncthreads();
    int s[8], d[8];
    const int base = b * 2048 + tid * 8;
    #pragma unroll
    for (int i = 0; i < 8; i++) {
      int g = base + i;
      bool ok = g < E;
      s[i] = ok ? src[g] : 0;
      d[i] = ok ? dst[g] : -1;
      if (ok) atomicAdd(&h[d[i] >> 8], 1);
    }
    __syncthreads();
    for (int i = tid; i < NB; i += 256) {
      rb[i] = h[i] ? atomicAdd(&cursor[i], h[i]) : 0;
      h[i] = 0;
    }
    __syncthreads();
    #pragma unroll
    for (int i = 0; i < 8; i++) {
      if (d[i] >= 0) {
        int bk = d[i] >> 8;
        int off = rb[bk] + atomicAdd(&h[bk], 1);
        if (off < SLAB)
          pairs[(size_t)bk * SLAB + off] =
              ((unsigned)(d[i] & 255) << 17) | (unsigned)s[i];
      }
    }
  } else if (b < SB + XB) {
    // ---- x fp32 -> bf16 row-major root rows ----
    int t = (b - SB) * 256 + tid;      // t < N*16
    int node = t >> 4, c = t & 15;
    const float4* xp = (const float4*)(x + (size_t)node * 128 + c * 8);
    float4 a = xp[0], bb = xp[1];
    float v[8] = {a.x, a.y, a.z, a.w, bb.x, bb.y, bb.z, bb.w};
    unsigned hh[8];
    #pragma unroll
    for (int i = 0; i < 8; i++) hh[i] = f2bf(v[i]);
    uint4 p;
    p.x = hh[0] | (hh[1] << 16); p.y = hh[2] | (hh[3] << 16);
    p.z = hh[4] | (hh[5] << 16); p.w = hh[6] | (hh[7] << 16);
    *(uint4*)(Zrm + (size_t)node * 128 + c * 8) = p;
  } else if (b < SB + XB + 64) {
    // ---- weight transpose, MFMA-fragment layout (single bf16 term) ----
    //   frag = (nn>>4)*8 + (k>>7)*4 + ((k>>5)&3); lane = ((k>>3)&3)*16+(nn&15)
    #pragma unroll
    for (int it = 0; it < 4; it++) {
      int t = (b - SB - XB) * 1024 + it * 256 + tid;  // t < 65536
      int layer = t >> 15;
      int rem = t & 32767;
      int k = rem >> 7;
      int nn = rem & 127;
      const float* Wl = layer ? W2l : W1l;
      const float* Wr = layer ? W2r : W1r;
      float v = (k < 128) ? Wl[k * 128 + nn] : Wr[(k - 128) * 128 + nn];
      unsigned short hv = f2bf(v);
      const int frag = (nn >> 4) * 8 + (k >> 7) * 4 + ((k >> 5) & 3);
      const int lane = ((k >> 3) & 3) * 16 + (nn & 15);
      const int addr = frag * 512 + lane * 8 + (k & 7);
      (layer ? wt2 : wt1)[addr] = hv;
    }
  } else {
    // ---- zero row N of Zrm (padding row for gather; stays 0 both layers) ----
    unsigned* zr = (unsigned*)(Zrm + (size_t)NN * 128);
    if (tid < 64) zr[tid] = 0;
  }
}

// ---------------- per-bucket CSR build ----------------
__global__ __launch_bounds__(256) void k_build(const unsigned* __restrict__ pairs,
                                               const int* __restrict__ cursor,
                                               int* __restrict__ beg, int* __restrict__ deg,
                                               int* __restrict__ csr, int N) {
  __shared__ int cnt[256];
  __shared__ int sd[256];
  __shared__ int cur[256];
  const int b = blockIdx.x;
  const int tid = threadIdx.x;
  const size_t p0 = (size_t)b * SLAB;
  int count = cursor[b];
  if (count > SLAB) count = SLAB;
  cnt[tid] = 0;
  cur[tid] = 0;
  __syncthreads();
  for (int i = tid; i < count; i += 256) atomicAdd(&cnt[pairs[p0 + i] >> 17], 1);
  __syncthreads();
  int v = cnt[tid];
  sd[tid] = v;
  __syncthreads();
  #pragma unroll
  for (int off = 1; off < 256; off <<= 1) {
    int u = (tid >= off) ? sd[tid - off] : 0;
    __syncthreads();
    sd[tid] += u;
    __syncthreads();
  }
  const int node = b * 256 + tid;
  if (node < N) {
    beg[node] = (int)p0 + (sd[tid] - v);
    deg[node] = v;
  }
  __syncthreads();
  for (int i = tid; i < count; i += 256) {
    unsigned pv = pairs[p0 + i];
    int dl = pv >> 17;
    int pos = (sd[dl] - cnt[dl]) + atomicAdd(&cur[dl], 1);
    csr[p0 + pos] = pv & 0x1ffff;
  }
}

// accumulate 8 bf16 (packed in uint4) into float acc[8] -- bit-exact unpack order
#define ACC8(v)                                   \
  acc[0] += uaf((v).x << 16);                     \
  acc[1] += uaf((v).x & 0xffff0000u);             \
  acc[2] += uaf((v).y << 16);                     \
  acc[3] += uaf((v).y & 0xffff0000u);             \
  acc[4] += uaf((v).z << 16);                     \
  acc[5] += uaf((v).z & 0xffff0000u);             \
  acc[6] += uaf((v).w << 16);                     \
  acc[7] += uaf((v).w & 0xffff0000u);

// ---------------- mean aggregation (R0 verified body; rm in, rm out) ----------------
__global__ __launch_bounds__(256) void k_aggZ(const unsigned short* __restrict__ Zrm,
                                              unsigned short* __restrict__ Zagg,
                                              const int* __restrict__ begA,
                                              const int* __restrict__ degA,
                                              const int* __restrict__ csr, int n) {
  const int wid = (blockIdx.x * blockDim.x + threadIdx.x) >> 6;
  const int lane = threadIdx.x & 63;
  if (wid >= n) return;
  const int beg = begA[wid];
  const int d = degA[wid];
  const int g = lane >> 4, c = lane & 15;
  float acc[8] = {0.f, 0.f, 0.f, 0.f, 0.f, 0.f, 0.f, 0.f};

  for (int base = 0; base < d; base += 64) {
    int m = d - base;
    if (m > 64) m = 64;
    int idx = csr[beg + base + (lane < m ? lane : 0)];
    for (int k = 0; k < m; k += 32) {
      uint4 vA[4], vB[4];
      const bool hasB = (k + 16) < m;
      #pragma unroll
      for (int u = 0; u < 4; u++) {
        int kk = k + u * 4 + g;
        int j = __shfl(idx, kk & 63);
        j = (kk < m) ? j : NN;  // zero row
        vA[u] = *(const uint4*)(Zrm + (size_t)j * 128 + c * 8);
      }
      if (hasB) {
        #pragma unroll
        for (int u = 0; u < 4; u++) {
          int kk = k + 16 + u * 4 + g;
          int j = __shfl(idx, kk & 63);
          j = (kk < m) ? j : NN;
          vB[u] = *(const uint4*)(Zrm + (size_t)j * 128 + c * 8);
        }
      }
      #pragma unroll
      for (int u = 0; u < 4; u++) { ACC8(vA[u]); }
      if (hasB) {
        #pragma unroll
        for (int u = 0; u < 4; u++) { ACC8(vB[u]); }
      }
    }
  }
  #pragma unroll
  for (int j = 0; j < 8; j++) {
    acc[j] += __shfl_xor(acc[j], 16);
    acc[j] += __shfl_xor(acc[j], 32);
  }
  const float inv = d > 0 ? 1.0f / (float)d : 0.f;
  if (g == 0) {
    unsigned h[8];
    #pragma unroll
    for (int j = 0; j < 8; j++) h[j] = f2bf(acc[j] * inv);
    uint4 p;
    p.x = h[0] | (h[1] << 16); p.y = h[2] | (h[3] << 16);
    p.z = h[4] | (h[5] << 16); p.w = h[6] | (h[7] << 16);
    *(uint4*)(Zagg + (size_t)wid * 128 + c * 8) = p;
  }
}

// ---------------- MFMA SAGE layer: LDS-staged tiles, single-term weights ----------------
// Per wave: 64 contiguous rows. Per kh half: stage 16KB (16 coalesced 1KB
// loads) into private swizzled LDS tile, read 16 ds_read_b128 fragments.
// acc[s][cc] = mfma(W_frag, Z_frag, acc) (swapped operands): lane holds
// feat f'=cc*16+r16*4+r of node m0+s*16+ln. 256 MFMA + 64 weight loads
// per wave (was 512 + 128 with the hi/lo split).
// MODE 0: relu -> Zout rows. MODE 1: fused layer-3 transform -> s2/r2.
template <int MODE>
__global__ __launch_bounds__(256, 2) void k_sage2(
    const unsigned short* __restrict__ Zagg, const unsigned short* __restrict__ Zroot,
    const unsigned short* __restrict__ WT, const float* __restrict__ bias,
    unsigned short* __restrict__ Zout,
    const float* __restrict__ w3l, const float* __restrict__ w3r,
    float* __restrict__ s2, float* __restrict__ r2, int n) {
  __shared__ __align__(16) unsigned short tile[4][8192];  // 16 KB per wave
  const int tid = threadIdx.x;
  const int lane = tid & 63;
  const int w = tid >> 6;
  const int ln = lane & 15;
  const int r16 = lane >> 4;
  const int m0 = blockIdx.x * 256 + w * 64;
  char* T = (char*)tile[w];

  f32x4 acc[4][8];
  #pragma unroll
  for (int s = 0; s < 4; s++)
    #pragma unroll
    for (int cc = 0; cc < 8; cc++) {
      acc[s][cc][0] = 0.f; acc[s][cc][1] = 0.f;
      acc[s][cc][2] = 0.f; acc[s][cc][3] = 0.f;
    }

  #pragma unroll
  for (int kh = 0; kh < 2; kh++) {
    const unsigned short* zsrc = kh ? Zroot : Zagg;
    // ---- stage 64 rows x 128 feats, XOR-swizzled (coalesced 1KB/instr) ----
    #pragma unroll
    for (int i = 0; i < 16; i++) {
      const int nl = i * 4 + r16;
      uint4 v = *(const uint4*)(zsrc + (size_t)(m0 + nl) * 128 + ln * 8);
      *(uint4*)(T + nl * 256 + ((ln * 16) ^ ((nl & 7) << 4))) = v;
    }
    // ---- fragment reads: a[s][ks][e] = Z[m0+s*16+ln][ks*32+r16*8+e] ----
    bf16x8 a[4][4];
    #pragma unroll
    for (int ks = 0; ks < 4; ks++)
      #pragma unroll
      for (int s = 0; s < 4; s++) {
        const int nl = s * 16 + ln;
        a[s][ks] = *(const bf16x8*)(T + nl * 256 +
                                    ((ks * 64 + r16 * 16) ^ ((nl & 7) << 4)));
      }
    // ---- MFMAs (single weight term; per-acc order preserved) ----
    #pragma unroll
    for (int ks = 0; ks < 4; ks++) {
      #pragma unroll
      for (int cg = 0; cg < 4; cg++) {
        bf16x8 bh[2];
        #pragma unroll
        for (int j = 0; j < 2; j++) {
          const size_t o = (size_t)(((cg * 2 + j) * 8 + kh * 4 + ks) * 512 + lane * 8);
          bh[j] = *(const bf16x8*)(WT + o);
        }
        #pragma unroll
        for (int j = 0; j < 2; j++) {
          #pragma unroll
          for (int s = 0; s < 4; s++) {
            acc[s][cg * 2 + j] =
                __builtin_amdgcn_mfma_f32_16x16x32_bf16(bh[j], a[s][ks], acc[s][cg * 2 + j], 0, 0, 0);
          }
        }
      }
    }
  }

  if (MODE == 0) {
    float4 bv4[8];
    #pragma unroll
    for (int cc = 0; cc < 8; cc++) bv4[cc] = *(const float4*)(bias + cc * 16 + r16 * 4);
    #pragma unroll
    for (int s = 0; s < 4; s++) {
      const int node = m0 + s * 16 + ln;
      if (node < n) {
        unsigned short* op = Zout + (size_t)node * 128 + r16 * 4;
        #pragma unroll
        for (int cc = 0; cc < 8; cc++) {
          ushort4 hq;
          hq.x = f2bf(fmaxf(acc[s][cc][0] + bv4[cc].x, 0.f));
          hq.y = f2bf(fmaxf(acc[s][cc][1] + bv4[cc].y, 0.f));
          hq.z = f2bf(fmaxf(acc[s][cc][2] + bv4[cc].z, 0.f));
          hq.w = f2bf(fmaxf(acc[s][cc][3] + bv4[cc].w, 0.f));
          *(ushort4*)(op + cc * 16) = hq;
        }
      }
    }
  } else {
    float4 bv4[8], wl4[8], wr4[8];
    #pragma unroll
    for (int cc = 0; cc < 8; cc++) {
      bv4[cc] = *(const float4*)(bias + cc * 16 + r16 * 4);
      wl4[cc] = *(const float4*)(w3l + cc * 16 + r16 * 4);
      wr4[cc] = *(const float4*)(w3r + cc * 16 + r16 * 4);
    }
    #pragma unroll
    for (int s = 0; s < 4; s++) {
      float sl = 0.f, sr = 0.f;
      #pragma unroll
      for (int cc = 0; cc < 8; cc++) {
        float v0 = fmaxf(acc[s][cc][0] + bv4[cc].x, 0.f);
        float v1 = fmaxf(acc[s][cc][1] + bv4[cc].y, 0.f);
        float v2 = fmaxf(acc[s][cc][2] + bv4[cc].z, 0.f);
        float v3 = fmaxf(acc[s][cc][3] + bv4[cc].w, 0.f);
        sl += v0 * wl4[cc].x + v1 * wl4[cc].y + v2 * wl4[cc].z + v3 * wl4[cc].w;
        sr += v0 * wr4[cc].x + v1 * wr4[cc].y + v2 * wr4[cc].z + v3 * wr4[cc].w;
      }
      sl += __shfl_xor(sl, 16); sl += __shfl_xor(sl, 32);
      sr += __shfl_xor(sr, 16); sr += __shfl_xor(sr, 32);
      const int node = m0 + s * 16 + ln;
      if (r16 == 0 && node < n) {
        s2[node] = sl;
        r2[node] = sr;
      }
    }
  }
}

// ---------------- final scalar aggregation (16 lanes/node) ----------------
__global__ __launch_bounds__(256) void k_out3(const float* __restrict__ s2,
                                              const float* __restrict__ r2,
                                              const int* __restrict__ beg,
                                              const int* __restrict__ deg,
                                              const int* __restrict__ csr,
                                              const float* __restrict__ b3,
                                              float* __restrict__ out, int n) {
  int t = blockIdx.x * blockDim.x + threadIdx.x;
  int node = t >> 4;
  int ln = t & 15;
  if (node >= n) return;
  int bg = beg[node], d = deg[node];
  float s = 0.f;
  for (int i = ln; i < d; i += 16) s += s2[csr[bg + i]];
  s += __shfl_xor(s, 1); s += __shfl_xor(s, 2);
  s += __shfl_xor(s, 4); s += __shfl_xor(s, 8);
  if (ln == 0) out[node] = s / (d > 0 ? (float)d : 1.0f) + r2[node] + b3[0];
}

extern "C" void kernel_launch(void* const* d_in, const int* in_sizes, int n_in,
                              void* d_out, int out_size, void* d_ws, size_t ws_size,
                              hipStream_t stream) {
  const float* x   = (const float*)d_in[0];
  const int*   ei  = (const int*)d_in[1];
  const float* W1l = (const float*)d_in[2];
  const float* W1r = (const float*)d_in[3];
  const float* b1  = (const float*)d_in[4];
  const float* W2l = (const float*)d_in[5];
  const float* W2r = (const float*)d_in[6];
  const float* b2  = (const float*)d_in[7];
  const float* W3l = (const float*)d_in[8];
  const float* W3r = (const float*)d_in[9];
  const float* b3  = (const float*)d_in[10];
  float* out = (float*)d_out;

  const int N = NN;
  const int E = in_sizes[1] / 2;
  const int* src = ei;
  const int* dst = ei + E;

  char* ws = (char*)d_ws;
  size_t off = 0;
  auto alloc = [&](size_t bytes) -> char* {
    char* p = ws + off;
    off = (off + bytes + 255) & ~(size_t)255;
    return p;
  };
  int* cursor = (int*)alloc((NB + 1) * 4);
  unsigned* pairs = (unsigned*)alloc((size_t)NB * SLAB * 4);
  int* csr  = (int*)alloc(((size_t)NB * SLAB + 128) * 4);
  int* beg  = (int*)alloc((size_t)N * 4);
  int* deg  = (int*)alloc((size_t)N * 4);
  float* s2 = (float*)alloc((size_t)N * 4);
  float* r2 = (float*)alloc((size_t)N * 4);
  unsigned short* wt1 = (unsigned short*)alloc(128 * 256 * 2);
  unsigned short* wt2 = (unsigned short*)alloc(128 * 256 * 2);
  // +160 slack rows: sage2 tail-block staging reads up to row 100,095;
  // row NN is the zero pad for the gather (prep zeroes it, epilogue guards it).
  unsigned short* Zrm  = (unsigned short*)alloc((size_t)(N + 160) * 128 * 2);
  unsigned short* Zagg = (unsigned short*)alloc((size_t)(N + 160) * 128 * 2);

  hipMemsetAsync(cursor, 0, (NB + 1) * 4, stream);

  // ---- fused prep: edge scatter | x->bf16 | weight cvt | zero row ----
  const int SB = (E + 2047) / 2048;         // 782 scatter blocks
  const int XB = N * 16 / 256;              // 6250 cvt_x blocks
  k_prep<<<SB + XB + 64 + 1, 256, 0, stream>>>(
      src, dst, E, SB, cursor, pairs, x, Zrm,
      W1l, W1r, W2l, W2r, wt1, wt2);
  k_build<<<NB, 256, 0, stream>>>(pairs, cursor, beg, deg, csr, N);

  const int wb = (N * 64 + 255) / 256;
  const int sb = (N + 255) / 256;           // 391 GEMM blocks (64 rows/wave)
  // ---- layer 1 ----
  k_aggZ<<<wb, 256, 0, stream>>>(Zrm, Zagg, beg, deg, csr, N);
  k_sage2<0><<<sb, 256, 0, stream>>>(Zagg, Zrm, wt1, b1, Zrm,
                                     nullptr, nullptr, nullptr, nullptr, N);
  // ---- layer 2 (+ fused layer-3 transform) ----
  k_aggZ<<<wb, 256, 0, stream>>>(Zrm, Zagg, beg, deg, csr, N);
  k_sage2<1><<<sb, 256, 0, stream>>>(Zagg, Zrm, wt2, b2, nullptr,
                                     W3l, W3r, s2, r2, N);
  // ---- layer 3 scalar aggregation ----
  k_out3<<<(N * 16 + 255) / 256, 256, 0, stream>>>(s2, r2, beg, deg, csr, b3, out, N);
}

// Round 16
// 221.221 us; speedup vs baseline: 1.2543x; 1.0918x over previous
//
#include <hip/hip_runtime.h>

// 3-layer GraphSAGE, N=100000, F=H=128, E=1.6M.
// bf16 features, single-term bf16 weights (R15).
// R13/R15 structure: row-major activations, per-wave LDS-staged A-tiles
// (XOR-swizzled), fragment-order weights, swapped-operand MFMA, coalesced
// epilogue, 64 rows/wave, 391 GEMM blocks.
// THIS VERSION: WEIGHTS STAGED IN BLOCK-SHARED LDS per kh-half.
//  - weight layout regrouped so each kh's 32KB is contiguous
//    (frag = kh*32 + cidx*4 + ks); block stages it cooperatively
//    (coalesced, 1 barrier), MFMA B-operands become linear conflict-free
//    ds_read_b128 -- removes 64x 1KB L2-latency weight loads per wave
//    (8 waves/CU x 64KB thrashed the 32KB L1; acc's 128 VGPR left no
//    registers to pipeline them).
//  - A-tile staged per feature-half (8KB/wave, restaged 2x/kh, same bytes)
//    so LDS/block = 32KB A + 32KB W = 64KB -> 2 blocks/CU retained.
// Per-acc MFMA order unchanged -> bit-identical to R15 (absmax 0.0117).
// aggZ = R0 verified body (gather structural: ~59us / 3.3TB/s fill wall,
// FETCH at per-XCD dedupe floor -- R1/R2/R3/R4/R6/R10 all refuted).

#define NN 100000
#define NB 391          // ceil(100000/256) buckets of 256 dst nodes
#define SLAB 5120       // slab capacity per bucket (mean 4096, sigma 64)

typedef short bf16x8 __attribute__((ext_vector_type(8)));
typedef float f32x4 __attribute__((ext_vector_type(4)));

static __device__ __forceinline__ float uaf(unsigned u) { return __uint_as_float(u); }
static __device__ __forceinline__ unsigned short f2bf(float f) {
  unsigned u = __float_as_uint(f);
  u += 0x7fffu + ((u >> 16) & 1u);
  return (unsigned short)(u >> 16);
}

// ---------------- fused prep: scatter | cvt_x | cvt_w | zero rows ----------------
__global__ __launch_bounds__(256) void k_prep(
    const int* __restrict__ src, const int* __restrict__ dst, int E, int SB,
    int* __restrict__ cursor, unsigned* __restrict__ pairs,
    const float* __restrict__ x, unsigned short* __restrict__ Zrm,
    const float* __restrict__ W1l, const float* __restrict__ W1r,
    const float* __restrict__ W2l, const float* __restrict__ W2r,
    unsigned short* __restrict__ wt1, unsigned short* __restrict__ wt2) {
  __shared__ int h[NB];
  __shared__ int rb[NB];
  const int b = blockIdx.x;
  const int tid = threadIdx.x;
  const int XB = NN * 16 / 256;  // 6250 cvt_x blocks

  if (b < SB) {
    // ---- edge scatter into bucket slabs ----
    for (int i = tid; i < NB; i += 256) h[i] = 0;
    __syncthreads();
    int s[8], d[8];
    const int base = b * 2048 + tid * 8;
    #pragma unroll
    for (int i = 0; i < 8; i++) {
      int g = base + i;
      bool ok = g < E;
      s[i] = ok ? src[g] : 0;
      d[i] = ok ? dst[g] : -1;
      if (ok) atomicAdd(&h[d[i] >> 8], 1);
    }
    __syncthreads();
    for (int i = tid; i < NB; i += 256) {
      rb[i] = h[i] ? atomicAdd(&cursor[i], h[i]) : 0;
      h[i] = 0;
    }
    __syncthreads();
    #pragma unroll
    for (int i = 0; i < 8; i++) {
      if (d[i] >= 0) {
        int bk = d[i] >> 8;
        int off = rb[bk] + atomicAdd(&h[bk], 1);
        if (off < SLAB)
          pairs[(size_t)bk * SLAB + off] =
              ((unsigned)(d[i] & 255) << 17) | (unsigned)s[i];
      }
    }
  } else if (b < SB + XB) {
    // ---- x fp32 -> bf16 row-major root rows ----
    int t = (b - SB) * 256 + tid;      // t < N*16
    int node = t >> 4, c = t & 15;
    const float4* xp = (const float4*)(x + (size_t)node * 128 + c * 8);
    float4 a = xp[0], bb = xp[1];
    float v[8] = {a.x, a.y, a.z, a.w, bb.x, bb.y, bb.z, bb.w};
    unsigned hh[8];
    #pragma unroll
    for (int i = 0; i < 8; i++) hh[i] = f2bf(v[i]);
    uint4 p;
    p.x = hh[0] | (hh[1] << 16); p.y = hh[2] | (hh[3] << 16);
    p.z = hh[4] | (hh[5] << 16); p.w = hh[6] | (hh[7] << 16);
    *(uint4*)(Zrm + (size_t)node * 128 + c * 8) = p;
  } else if (b < SB + XB + 64) {
    // ---- weight transpose, MFMA-fragment layout, kh-contiguous halves ----
    //   frag = kh*32 + cidx*4 + ks = (k>>7)*32 + (nn>>4)*4 + ((k>>5)&3)
    //   lane = ((k>>3)&3)*16 + (nn&15); addr = frag*512 + lane*8 + (k&7)
    #pragma unroll
    for (int it = 0; it < 4; it++) {
      int t = (b - SB - XB) * 1024 + it * 256 + tid;  // t < 65536
      int layer = t >> 15;
      int rem = t & 32767;
      int k = rem >> 7;
      int nn = rem & 127;
      const float* Wl = layer ? W2l : W1l;
      const float* Wr = layer ? W2r : W1r;
      float v = (k < 128) ? Wl[k * 128 + nn] : Wr[(k - 128) * 128 + nn];
      unsigned short hv = f2bf(v);
      const int frag = (k >> 7) * 32 + (nn >> 4) * 4 + ((k >> 5) & 3);
      const int lane = ((k >> 3) & 3) * 16 + (nn & 15);
      const int addr = frag * 512 + lane * 8 + (k & 7);
      (layer ? wt2 : wt1)[addr] = hv;
    }
  } else {
    // ---- zero row N of Zrm (padding row for gather; stays 0 both layers) ----
    unsigned* zr = (unsigned*)(Zrm + (size_t)NN * 128);
    if (tid < 64) zr[tid] = 0;
  }
}

// ---------------- per-bucket CSR build ----------------
__global__ __launch_bounds__(256) void k_build(const unsigned* __restrict__ pairs,
                                               const int* __restrict__ cursor,
                                               int* __restrict__ beg, int* __restrict__ deg,
                                               int* __restrict__ csr, int N) {
  __shared__ int cnt[256];
  __shared__ int sd[256];
  __shared__ int cur[256];
  const int b = blockIdx.x;
  const int tid = threadIdx.x;
  const size_t p0 = (size_t)b * SLAB;
  int count = cursor[b];
  if (count > SLAB) count = SLAB;
  cnt[tid] = 0;
  cur[tid] = 0;
  __syncthreads();
  for (int i = tid; i < count; i += 256) atomicAdd(&cnt[pairs[p0 + i] >> 17], 1);
  __syncthreads();
  int v = cnt[tid];
  sd[tid] = v;
  __syncthreads();
  #pragma unroll
  for (int off = 1; off < 256; off <<= 1) {
    int u = (tid >= off) ? sd[tid - off] : 0;
    __syncthreads();
    sd[tid] += u;
    __syncthreads();
  }
  const int node = b * 256 + tid;
  if (node < N) {
    beg[node] = (int)p0 + (sd[tid] - v);
    deg[node] = v;
  }
  __syncthreads();
  for (int i = tid; i < count; i += 256) {
    unsigned pv = pairs[p0 + i];
    int dl = pv >> 17;
    int pos = (sd[dl] - cnt[dl]) + atomicAdd(&cur[dl], 1);
    csr[p0 + pos] = pv & 0x1ffff;
  }
}

// accumulate 8 bf16 (packed in uint4) into float acc[8] -- bit-exact unpack order
#define ACC8(v)                                   \
  acc[0] += uaf((v).x << 16);                     \
  acc[1] += uaf((v).x & 0xffff0000u);             \
  acc[2] += uaf((v).y << 16);                     \
  acc[3] += uaf((v).y & 0xffff0000u);             \
  acc[4] += uaf((v).z << 16);                     \
  acc[5] += uaf((v).z & 0xffff0000u);             \
  acc[6] += uaf((v).w << 16);                     \
  acc[7] += uaf((v).w & 0xffff0000u);

// ---------------- mean aggregation (R0 verified body; rm in, rm out) ----------------
__global__ __launch_bounds__(256) void k_aggZ(const unsigned short* __restrict__ Zrm,
                                              unsigned short* __restrict__ Zagg,
                                              const int* __restrict__ begA,
                                              const int* __restrict__ degA,
                                              const int* __restrict__ csr, int n) {
  const int wid = (blockIdx.x * blockDim.x + threadIdx.x) >> 6;
  const int lane = threadIdx.x & 63;
  if (wid >= n) return;
  const int beg = begA[wid];
  const int d = degA[wid];
  const int g = lane >> 4, c = lane & 15;
  float acc[8] = {0.f, 0.f, 0.f, 0.f, 0.f, 0.f, 0.f, 0.f};

  for (int base = 0; base < d; base += 64) {
    int m = d - base;
    if (m > 64) m = 64;
    int idx = csr[beg + base + (lane < m ? lane : 0)];
    for (int k = 0; k < m; k += 32) {
      uint4 vA[4], vB[4];
      const bool hasB = (k + 16) < m;
      #pragma unroll
      for (int u = 0; u < 4; u++) {
        int kk = k + u * 4 + g;
        int j = __shfl(idx, kk & 63);
        j = (kk < m) ? j : NN;  // zero row
        vA[u] = *(const uint4*)(Zrm + (size_t)j * 128 + c * 8);
      }
      if (hasB) {
        #pragma unroll
        for (int u = 0; u < 4; u++) {
          int kk = k + 16 + u * 4 + g;
          int j = __shfl(idx, kk & 63);
          j = (kk < m) ? j : NN;
          vB[u] = *(const uint4*)(Zrm + (size_t)j * 128 + c * 8);
        }
      }
      #pragma unroll
      for (int u = 0; u < 4; u++) { ACC8(vA[u]); }
      if (hasB) {
        #pragma unroll
        for (int u = 0; u < 4; u++) { ACC8(vB[u]); }
      }
    }
  }
  #pragma unroll
  for (int j = 0; j < 8; j++) {
    acc[j] += __shfl_xor(acc[j], 16);
    acc[j] += __shfl_xor(acc[j], 32);
  }
  const float inv = d > 0 ? 1.0f / (float)d : 0.f;
  if (g == 0) {
    unsigned h[8];
    #pragma unroll
    for (int j = 0; j < 8; j++) h[j] = f2bf(acc[j] * inv);
    uint4 p;
    p.x = h[0] | (h[1] << 16); p.y = h[2] | (h[3] << 16);
    p.z = h[4] | (h[5] << 16); p.w = h[6] | (h[7] << 16);
    *(uint4*)(Zagg + (size_t)wid * 128 + c * 8) = p;
  }
}

// ---------------- MFMA SAGE layer: LDS weights + half-feature A tiles ----------------
// Per kh: block stages this kh's 32KB weight half into wlds (coalesced,
// barrier); per feature-half: wave stages 64 rows x 64 feats (8KB,
// swizzled), reads A frags + W frags as conflict-free ds_read_b128.
// acc[s][cc] = mfma(W_frag, Z_frag, acc): lane holds feat f'=cc*16+r16*4+r
// of node m0+s*16+ln. Per-acc MFMA order = R15 -> bit-identical.
// MODE 0: relu -> Zout rows. MODE 1: fused layer-3 transform -> s2/r2.
template <int MODE>
__global__ __launch_bounds__(256, 2) void k_sage2(
    const unsigned short* __restrict__ Zagg, const unsigned short* __restrict__ Zroot,
    const unsigned short* __restrict__ WT, const float* __restrict__ bias,
    unsigned short* __restrict__ Zout,
    const float* __restrict__ w3l, const float* __restrict__ w3r,
    float* __restrict__ s2, float* __restrict__ r2, int n) {
  __shared__ __align__(16) unsigned short wlds[16384];    // 32 KB W half (block-shared)
  __shared__ __align__(16) unsigned short tile[4][4096];  // 8 KB per wave A half-tile
  const int tid = threadIdx.x;
  const int lane = tid & 63;
  const int w = tid >> 6;
  const int ln = lane & 15;
  const int r16 = lane >> 4;
  const int m0 = blockIdx.x * 256 + w * 64;
  char* T = (char*)tile[w];
  const int srow = lane >> 3;   // stage row-in-group 0..7
  const int schk = lane & 7;    // stage 16B chunk 0..7

  f32x4 acc[4][8];
  #pragma unroll
  for (int s = 0; s < 4; s++)
    #pragma unroll
    for (int cc = 0; cc < 8; cc++) {
      acc[s][cc][0] = 0.f; acc[s][cc][1] = 0.f;
      acc[s][cc][2] = 0.f; acc[s][cc][3] = 0.f;
    }

  #pragma unroll
  for (int kh = 0; kh < 2; kh++) {
    const unsigned short* zsrc = kh ? Zroot : Zagg;
    // ---- block-cooperative W stage (this kh's contiguous 32KB) ----
    __syncthreads();   // all waves done reading previous kh's wlds
    {
      const unsigned short* wsrc = WT + (size_t)kh * 16384;
      #pragma unroll
      for (int i = 0; i < 8; i++) {
        const int t = i * 256 + tid;   // 2048 x 16B = 32KB
        *(uint4*)(wlds + (size_t)t * 8) = *(const uint4*)(wsrc + (size_t)t * 8);
      }
    }
    __syncthreads();
    #pragma unroll
    for (int half = 0; half < 2; half++) {
      // ---- stage A: 64 rows x 64 feats (128B/row), swizzled ----
      #pragma unroll
      for (int i = 0; i < 8; i++) {
        const int rr = i * 8 + srow;
        uint4 v = *(const uint4*)(zsrc + (size_t)(m0 + rr) * 128 + half * 64 + schk * 8);
        *(uint4*)(T + rr * 128 + ((schk * 16) ^ ((rr & 7) << 4))) = v;
      }
      // ---- A fragment reads: a[s][k2][e] = Z[m0+s*16+ln][(half*2+k2)*32+r16*8+e]
      bf16x8 a[4][2];
      #pragma unroll
      for (int k2 = 0; k2 < 2; k2++)
        #pragma unroll
        for (int s = 0; s < 4; s++) {
          const int nl = s * 16 + ln;
          a[s][k2] = *(const bf16x8*)(T + nl * 128 +
                                      ((k2 * 64 + r16 * 16) ^ ((nl & 7) << 4)));
        }
      // ---- MFMAs (W from LDS; per-acc order = R15) ----
      #pragma unroll
      for (int k2 = 0; k2 < 2; k2++) {
        const int ks = half * 2 + k2;
        #pragma unroll
        for (int cg = 0; cg < 4; cg++) {
          bf16x8 bh[2];
          #pragma unroll
          for (int j = 0; j < 2; j++)
            bh[j] = *(const bf16x8*)(wlds +
                     (size_t)(((cg * 2 + j) * 4 + ks) * 512 + lane * 8));
          #pragma unroll
          for (int j = 0; j < 2; j++) {
            #pragma unroll
            for (int s = 0; s < 4; s++) {
              acc[s][cg * 2 + j] =
                  __builtin_amdgcn_mfma_f32_16x16x32_bf16(bh[j], a[s][k2], acc[s][cg * 2 + j], 0, 0, 0);
            }
          }
        }
      }
    }
  }

  if (MODE == 0) {
    float4 bv4[8];
    #pragma unroll
    for (int cc = 0; cc < 8; cc++) bv4[cc] = *(const float4*)(bias + cc * 16 + r16 * 4);
    #pragma unroll
    for (int s = 0; s < 4; s++) {
      const int node = m0 + s * 16 + ln;
      if (node < n) {
        unsigned short* op = Zout + (size_t)node * 128 + r16 * 4;
        #pragma unroll
        for (int cc = 0; cc < 8; cc++) {
          ushort4 hq;
          hq.x = f2bf(fmaxf(acc[s][cc][0] + bv4[cc].x, 0.f));
          hq.y = f2bf(fmaxf(acc[s][cc][1] + bv4[cc].y, 0.f));
          hq.z = f2bf(fmaxf(acc[s][cc][2] + bv4[cc].z, 0.f));
          hq.w = f2bf(fmaxf(acc[s][cc][3] + bv4[cc].w, 0.f));
          *(ushort4*)(op + cc * 16) = hq;
        }
      }
    }
  } else {
    float4 bv4[8], wl4[8], wr4[8];
    #pragma unroll
    for (int cc = 0; cc < 8; cc++) {
      bv4[cc] = *(const float4*)(bias + cc * 16 + r16 * 4);
      wl4[cc] = *(const float4*)(w3l + cc * 16 + r16 * 4);
      wr4[cc] = *(const float4*)(w3r + cc * 16 + r16 * 4);
    }
    #pragma unroll
    for (int s = 0; s < 4; s++) {
      float sl = 0.f, sr = 0.f;
      #pragma unroll
      for (int cc = 0; cc < 8; cc++) {
        float v0 = fmaxf(acc[s][cc][0] + bv4[cc].x, 0.f);
        float v1 = fmaxf(acc[s][cc][1] + bv4[cc].y, 0.f);
        float v2 = fmaxf(acc[s][cc][2] + bv4[cc].z, 0.f);
        float v3 = fmaxf(acc[s][cc][3] + bv4[cc].w, 0.f);
        sl += v0 * wl4[cc].x + v1 * wl4[cc].y + v2 * wl4[cc].z + v3 * wl4[cc].w;
        sr += v0 * wr4[cc].x + v1 * wr4[cc].y + v2 * wr4[cc].z + v3 * wr4[cc].w;
      }
      sl += __shfl_xor(sl, 16); sl += __shfl_xor(sl, 32);
      sr += __shfl_xor(sr, 16); sr += __shfl_xor(sr, 32);
      const int node = m0 + s * 16 + ln;
      if (r16 == 0 && node < n) {
        s2[node] = sl;
        r2[node] = sr;
      }
    }
  }
}

// ---------------- final scalar aggregation (16 lanes/node) ----------------
__global__ __launch_bounds__(256) void k_out3(const float* __restrict__ s2,
                                              const float* __restrict__ r2,
                                              const int* __restrict__ beg,
                                              const int* __restrict__ deg,
                                              const int* __restrict__ csr,
                                              const float* __restrict__ b3,
                                              float* __restrict__ out, int n) {
  int t = blockIdx.x * blockDim.x + threadIdx.x;
  int node = t >> 4;
  int ln = t & 15;
  if (node >= n) return;
  int bg = beg[node], d = deg[node];
  float s = 0.f;
  for (int i = ln; i < d; i += 16) s += s2[csr[bg + i]];
  s += __shfl_xor(s, 1); s += __shfl_xor(s, 2);
  s += __shfl_xor(s, 4); s += __shfl_xor(s, 8);
  if (ln == 0) out[node] = s / (d > 0 ? (float)d : 1.0f) + r2[node] + b3[0];
}

extern "C" void kernel_launch(void* const* d_in, const int* in_sizes, int n_in,
                              void* d_out, int out_size, void* d_ws, size_t ws_size,
                              hipStream_t stream) {
  const float* x   = (const float*)d_in[0];
  const int*   ei  = (const int*)d_in[1];
  const float* W1l = (const float*)d_in[2];
  const float* W1r = (const float*)d_in[3];
  const float* b1  = (const float*)d_in[4];
  const float* W2l = (const float*)d_in[5];
  const float* W2r = (const float*)d_in[6];
  const float* b2  = (const float*)d_in[7];
  const float* W3l = (const float*)d_in[8];
  const float* W3r = (const float*)d_in[9];
  const float* b3  = (const float*)d_in[10];
  float* out = (float*)d_out;

  const int N = NN;
  const int E = in_sizes[1] / 2;
  const int* src = ei;
  const int* dst = ei + E;

  char* ws = (char*)d_ws;
  size_t off = 0;
  auto alloc = [&](size_t bytes) -> char* {
    char* p = ws + off;
    off = (off + bytes + 255) & ~(size_t)255;
    return p;
  };
  int* cursor = (int*)alloc((NB + 1) * 4);
  unsigned* pairs = (unsigned*)alloc((size_t)NB * SLAB * 4);
  int* csr  = (int*)alloc(((size_t)NB * SLAB + 128) * 4);
  int* beg  = (int*)alloc((size_t)N * 4);
  int* deg  = (int*)alloc((size_t)N * 4);
  float* s2 = (float*)alloc((size_t)N * 4);
  float* r2 = (float*)alloc((size_t)N * 4);
  unsigned short* wt1 = (unsigned short*)alloc(128 * 256 * 2);
  unsigned short* wt2 = (unsigned short*)alloc(128 * 256 * 2);
  // +160 slack rows: sage2 tail-block staging reads up to row 100,095;
  // row NN is the zero pad for the gather (prep zeroes it, epilogue guards it).
  unsigned short* Zrm  = (unsigned short*)alloc((size_t)(N + 160) * 128 * 2);
  unsigned short* Zagg = (unsigned short*)alloc((size_t)(N + 160) * 128 * 2);

  hipMemsetAsync(cursor, 0, (NB + 1) * 4, stream);

  // ---- fused prep: edge scatter | x->bf16 | weight cvt | zero row ----
  const int SB = (E + 2047) / 2048;         // 782 scatter blocks
  const int XB = N * 16 / 256;              // 6250 cvt_x blocks
  k_prep<<<SB + XB + 64 + 1, 256, 0, stream>>>(
      src, dst, E, SB, cursor, pairs, x, Zrm,
      W1l, W1r, W2l, W2r, wt1, wt2);
  k_build<<<NB, 256, 0, stream>>>(pairs, cursor, beg, deg, csr, N);

  const int wb = (N * 64 + 255) / 256;
  const int sb = (N + 255) / 256;           // 391 GEMM blocks (64 rows/wave)
  // ---- layer 1 ----
  k_aggZ<<<wb, 256, 0, stream>>>(Zrm, Zagg, beg, deg, csr, N);
  k_sage2<0><<<sb, 256, 0, stream>>>(Zagg, Zrm, wt1, b1, Zrm,
                                     nullptr, nullptr, nullptr, nullptr, N);
  // ---- layer 2 (+ fused layer-3 transform) ----
  k_aggZ<<<wb, 256, 0, stream>>>(Zrm, Zagg, beg, deg, csr, N);
  k_sage2<1><<<sb, 256, 0, stream>>>(Zagg, Zrm, wt2, b2, nullptr,
                                     W3l, W3r, s2, r2, N);
  // ---- layer 3 scalar aggregation ----
  k_out3<<<(N * 16 + 255) / 256, 256, 0, stream>>>(s2, r2, beg, deg, csr, b3, out, N);
}